// Round 1
// baseline (271.180 us; speedup 1.0000x reference)
//
#include <hip/hip_runtime.h>
#include <hip/hip_bf16.h>
#include <math.h>

// H2R detector: score map -> 3x3 NMS peaks -> per-batch top-1000 -> ROIs.
// [B=32,1,512,512] fp32 inputs; out = rois[32,1000,5] ++ scores[32,1000]
// ++ valid[32,1000] = 224000 floats.
//
// Scoring replicates numpy's SIMD (Cephes) fp32 expf op-for-op (verified
// bit-exact rounds 5-10: absmax 0.0). DO NOT alter score or emit paths.
//
// Round 12: select_kernel (42us, 32 blocks = 1/8 machine, latency-bound)
// split apart for parallelism:
//   - histogram folded into fused_peak (full-machine occupancy): peak
//     buckets recorded in registers during peak loop, accumulated into the
//     dead sm[] LDS overlay (no extra LDS -> occupancy unchanged), merged
//     into a global per-batch hist via atomics (~900/block).
//   - gather_kernel grid(8,32) = 256 blocks: per-block T-scan from global
//     hist (early-break), ballot-aggregated append to global cand buffer.
//   - sort_emit_kernel (32 blocks): verified bitonic sort + emit, verbatim.
//   - hipMemsetAsync zeroes ghist+gcnt (512KB) before fused_peak.

#define B_   32
#define H_   512
#define W_   512
#define HW_  (H_ * W_)
#define K_   1000
#define ROWS_ 16            // interior rows per strip
#define THR_  512           // threads per fused block (8 waves)
#define NSTRIP_ 32          // H_/ROWS_
#define SEGCAP_ 1200        // per-strip peak capacity (mean ~900; even -> 16B seg align)
#define NSLOT_ (NSTRIP_ * SEGCAP_)   // 38400 slots per batch
#define NPAIR_ (NSLOT_ / 2)          // 19200 ulonglong2 pairs
#define CAND_ 2048          // candidate buffer (power of 2)
#define NBUK_ 4096          // score buckets = bits >> 18 (score < 1.0)
#define GSPLIT_ 8           // gather blocks per batch

#define PL_BYTES_ ((size_t)B_ * NSLOT_ * 8)       // 9,830,400
#define GH_BYTES_ ((size_t)B_ * NBUK_ * 4)        // 524,288

// ---- numpy SIMD (Cephes) fp32 exp replica — bit-exact, do not touch -------
__device__ __forceinline__ float np_expf(float x) {
#pragma clang fp contract(off)
    const float log2e = 1.44269504088896341f;
    float z = x * log2e;
    float m = rintf(z);
    float r = fmaf(m, -0.693359375f, x);
    r = fmaf(m, 2.12194440e-4f, r);
    float r2 = r * r;
    float p = fmaf(1.9875691500e-4f, r, 1.3981999507e-3f);
    p = fmaf(p, r, 8.3334519073e-3f);
    p = fmaf(p, r, 4.1665795894e-2f);
    p = fmaf(p, r, 1.6666665459e-1f);
    p = fmaf(p, r, 5.0000001201e-1f);
    p = fmaf(p, r2, r);
    p = p + 1.0f;
    int mi = (int)m;
    float sc = __int_as_float((127 + mi) << 23);
    return p * sc;
}

__device__ __forceinline__ float sigmoid_np(float x) {
#pragma clang fp contract(off)
    float e = np_expf(-x);
    float d = 1.0f + e;
    return 1.0f / d;
}

__device__ __forceinline__ float score_ref(float r, float u) {
#pragma clang fp contract(off)
    float s  = sigmoid_np(r);
    float s2 = s * s;
    float su = sigmoid_np(u);
    float t  = 0.35f * su;
    float m  = 1.0f - t;
    return s2 * m;
}

__device__ __forceinline__ float sigmoid_fast(float x) {  // box geometry only
    return 1.0f / (1.0f + __expf(-x));
}

// ---- Fused: score strip + 3x3 peak test -> zero-padded segment + hist -----
__global__ __launch_bounds__(THR_, 4) void fused_peak_kernel(
    const float* __restrict__ route, const float* __restrict__ unc,
    unsigned long long* __restrict__ plist,
    unsigned int* __restrict__ ghist)
{
    __shared__ float sm[ROWS_ + 2][W_];          // 18x512 = 36.9 KB
    __shared__ int lcnt;

    const int tid   = threadIdx.x;
    const int lane  = tid & 63;
    const int strip = blockIdx.x;                // 0..31
    const int b     = blockIdx.y;                // 0..31
    const int r0    = strip * ROWS_;
    if (tid == 0) lcnt = 0;

    const float4* rb4 = (const float4*)(route + (size_t)b * HW_);
    const float4* ub4 = (const float4*)(unc   + (size_t)b * HW_);
    unsigned long long* seg =
        plist + (size_t)(b * NSTRIP_ + strip) * SEGCAP_;

    // Stage 18 halo rows: branchless (slot clamp), 10 loads in flight.
    float4 rv[5], uv[5];
    int lrow[5], c4[5]; bool ok[5];
    #pragma unroll
    for (int k = 0; k < 5; ++k) {
        int slot = tid + k * THR_;
        slot = slot < 2303 ? slot : 2303;
        int row = slot >> 7;
        int gy  = r0 - 1 + row;
        lrow[k] = row; c4[k] = slot & 127;
        ok[k]   = (gy >= 0 && gy < H_);
        int cy  = gy < 0 ? 0 : (gy >= H_ ? H_ - 1 : gy);
        rv[k] = rb4[cy * 128 + c4[k]];
        uv[k] = ub4[cy * 128 + c4[k]];
    }
    #pragma unroll
    for (int k = 0; k < 5; ++k) {
        float4 s;
        s.x = score_ref(rv[k].x, uv[k].x);
        s.y = score_ref(rv[k].y, uv[k].y);
        s.z = score_ref(rv[k].z, uv[k].z);
        s.w = score_ref(rv[k].w, uv[k].w);
        if (!ok[k]) { s.x = -INFINITY; s.y = -INFINITY;
                      s.z = -INFINITY; s.w = -INFINITY; }
        *(float4*)&sm[lrow[k]][c4[k] * 4] = s;
    }
    __syncthreads();

    // Peak test: 16x512 interior, 4-px groups, float4 reads + column max.
    // Buckets of stored peaks recorded in registers (2x16-bit per word).
    unsigned int hreg[8];
    #pragma unroll
    for (int j = 0; j < 4; ++j) {
        int g  = tid + j * THR_;                 // 0..2047
        int ly = 1 + (g >> 7);                   // 1..16
        int x0 = (g & 127) * 4;
        int gy = r0 + (ly - 1);
        float4 q0 = *(const float4*)&sm[ly - 1][x0];
        float4 q1 = *(const float4*)&sm[ly    ][x0];
        float4 q2 = *(const float4*)&sm[ly + 1][x0];
        bool hasL = (x0 > 0), hasR = (x0 + 4 < W_);
        float l0 = hasL ? sm[ly - 1][x0 - 1] : -INFINITY;
        float l1 = hasL ? sm[ly    ][x0 - 1] : -INFINITY;
        float l2 = hasL ? sm[ly + 1][x0 - 1] : -INFINITY;
        float e0 = hasR ? sm[ly - 1][x0 + 4] : -INFINITY;
        float e1 = hasR ? sm[ly    ][x0 + 4] : -INFINITY;
        float e2 = hasR ? sm[ly + 1][x0 + 4] : -INFINITY;
        float f_m1 = fmaxf(l0, fmaxf(l1, l2));
        float f_0  = fmaxf(q0.x, fmaxf(q1.x, q2.x));
        float f_1  = fmaxf(q0.y, fmaxf(q1.y, q2.y));
        float f_2  = fmaxf(q0.z, fmaxf(q1.z, q2.z));
        float f_3  = fmaxf(q0.w, fmaxf(q1.w, q2.w));
        float f_4  = fmaxf(e0, fmaxf(e1, e2));
        float tb0  = fmaxf(q0.x, q2.x);
        float tb1  = fmaxf(q0.y, q2.y);
        float tb2  = fmaxf(q0.z, q2.z);
        float tb3  = fmaxf(q0.w, q2.w);
        float vv[4] = { q1.x, q1.y, q1.z, q1.w };
        float mm[4];
        mm[0] = fmaxf(fmaxf(f_m1, f_1), tb0);
        mm[1] = fmaxf(fmaxf(f_0,  f_2), tb1);
        mm[2] = fmaxf(fmaxf(f_1,  f_3), tb2);
        mm[3] = fmaxf(fmaxf(f_2,  f_4), tb3);
        unsigned int pk01 = 0u, pk23 = 0u;
        #pragma unroll
        for (int i = 0; i < 4; ++i) {
            bool take = (vv[i] >= mm[i]);
            unsigned long long mk = __ballot(take);
            if (mk) {
                int ldr = __ffsll((unsigned long long)mk) - 1;
                int base_ = 0;
                if (lane == ldr) base_ = atomicAdd(&lcnt, __popcll(mk));
                base_ = __shfl(base_, ldr, 64);
                if (take) {
                    int p = base_ + __popcll(mk & ((1ull << lane) - 1ull));
                    unsigned int bits = __float_as_uint(vv[i]);
                    unsigned int idx  = (unsigned int)(gy * W_ + x0 + i);
                    if (p < SEGCAP_) {
                        seg[p] = ((unsigned long long)bits << 32)
                                 | (0xFFFFFFFFu - idx);
                        unsigned int bkt = bits >> 18;   // <4096, fits 16b
                        if (i < 2) pk01 |= bkt << (16 * i);
                        else       pk23 |= bkt << (16 * (i - 2));
                    }
                }
            }
        }
        hreg[2 * j]     = pk01;
        hreg[2 * j + 1] = pk23;
    }
    __syncthreads();

    // sm[] is dead now: overlay a 4096 x u32 histogram (16 KB of 36.9 KB).
    unsigned int* hist = (unsigned int*)&sm[0][0];
    for (int i = tid; i < NBUK_; i += THR_) hist[i] = 0u;
    // Zero-fill the seg tail so gather can stream the region unconditionally.
    int n = lcnt < SEGCAP_ ? lcnt : SEGCAP_;
    for (int i = n + tid; i < SEGCAP_; i += THR_) seg[i] = 0ull;
    __syncthreads();

    #pragma unroll
    for (int j = 0; j < 8; ++j) {
        unsigned int h  = hreg[j];
        unsigned int b0 = h & 0xFFFFu;
        unsigned int b1 = h >> 16;
        if (b0) atomicAdd(&hist[b0], 1u);
        if (b1) atomicAdd(&hist[b1], 1u);
    }
    __syncthreads();

    // Merge nonzero buckets into the global per-batch histogram.
    unsigned int* gh = ghist + (size_t)b * NBUK_;
    for (int i = tid; i < NBUK_; i += THR_) {
        unsigned int c = hist[i];
        if (c) atomicAdd(&gh[i], c);
    }
}

// ---- Gather: per-block T-scan from global hist -> global cand append ------
__global__ __launch_bounds__(1024) void gather_kernel(
    const unsigned long long* __restrict__ plist,
    const unsigned int* __restrict__ ghist,
    int* __restrict__ gcnt,
    unsigned long long* __restrict__ gcand)
{
    __shared__ int sh_T;

    const int sp  = blockIdx.x;                  // 0..GSPLIT_-1
    const int b   = blockIdx.y;                  // 0..31
    const int tid = threadIdx.x;
    const int lane = tid & 63, wid = tid >> 6;

    const ulonglong2* p2 = (const ulonglong2*)(plist + (size_t)b * NSLOT_);
    const int i0 = sp * (NPAIR_ / GSPLIT_);
    const int i1 = i0 + (NPAIR_ / GSPLIT_);

    // Preload this block's slice (<=3 iters) so loads overlap the T-scan.
    ulonglong2 a[3]; int ni = 0;
    {
        int k = 0;
        for (int i = i0 + tid; i < i1; i += 1024, ++k) a[k] = p2[i];
        ni = k;
    }

    // Wave 0: largest bucket T with count(>=T) >= K (early-break from top).
    if (tid == 0) sh_T = 0;
    if (wid == 0) {
        const unsigned int* gh = ghist + (size_t)b * NBUK_;
        int total = 0;
        for (int c = NBUK_ / 64 - 1; c >= 0; --c) {
            int cnt = (int)gh[c * 64 + lane];
            int sum = cnt;
            #pragma unroll
            for (int off = 32; off > 0; off >>= 1)
                sum += __shfl_down(sum, off, 64);
            sum = __shfl(sum, 0, 64);
            if (total + sum < K_) { total += sum; continue; }
            int suf = cnt;
            #pragma unroll
            for (int off = 1; off < 64; off <<= 1) {
                int o = __shfl_down(suf, off, 64);
                suf += (lane + off < 64) ? o : 0;
            }
            bool cond = (total + suf) >= K_;
            unsigned long long mask = __ballot(cond);
            int ls = 63 - __builtin_clzll(mask);
            if (lane == 0) sh_T = c * 64 + ls;
            break;
        }
    }
    __syncthreads();
    unsigned int T = (unsigned int)sh_T;
    if (T == 0u) T = 1u;   // never gather zero-keys (padding)

    int* cnt = gcnt + b;
    unsigned long long* cd = gcand + (size_t)b * CAND_;
    for (int k = 0; k < ni; ++k) {
        unsigned long long ks[2] = { a[k].x, a[k].y };
        #pragma unroll
        for (int q = 0; q < 2; ++q) {
            bool take = ((((unsigned int)(ks[q] >> 32))) >> 18) >= T;
            unsigned long long mk = __ballot(take);
            if (mk) {
                int ldr = __ffsll((unsigned long long)mk) - 1;
                int base_ = 0;
                if (lane == ldr) base_ = atomicAdd(cnt, __popcll(mk));
                base_ = __shfl(base_, ldr, 64);
                if (take) {
                    int p = base_ + __popcll(mk & ((1ull << lane) - 1ull));
                    if (p < CAND_) cd[p] = ks[q];
                }
            }
        }
    }
}

// ---- Sort + emit: bitonic (desc, exact 64-bit key) then verified emit -----
__global__ __launch_bounds__(1024) void sort_emit_kernel(
    const float* __restrict__ scale, const float* __restrict__ unc,
    const unsigned long long* __restrict__ gcand,
    const int* __restrict__ gcnt,
    const int* __restrict__ ih_p, const int* __restrict__ iw_p,
    float* __restrict__ out)
{
    __shared__ unsigned long long cand[CAND_];   // 16 KB

    const int b = blockIdx.x, tid = threadIdx.x;
    int nc = gcnt[b]; if (nc > CAND_) nc = CAND_;
    int sortN = (nc <= 1024) ? 1024 : CAND_;
    const unsigned long long* cd = gcand + (size_t)b * CAND_;
    for (int i = tid; i < sortN; i += 1024)
        cand[i] = (i < nc) ? cd[i] : 0ull;

    // Pair-indexed bitonic sort (desc, exact 64-bit key)
    for (int kk = 2; kk <= sortN; kk <<= 1) {
        for (int jj = kk >> 1; jj > 0; jj >>= 1) {
            __syncthreads();
            for (int p = tid; p < (sortN >> 1); p += 1024) {
                int i   = ((p & ~(jj - 1)) << 1) | (p & (jj - 1));
                int ixj = i | jj;
                bool desc = ((i & kk) == 0);
                unsigned long long a = cand[i], c2 = cand[ixj];
                if (desc ? (a < c2) : (a > c2)) { cand[i] = c2; cand[ixj] = a; }
            }
        }
    }
    __syncthreads();

    // Emit top-K (verified path — do not touch)
    const float fih = (float)(*ih_p);
    const float fiw = (float)(*iw_p);
    float* rois   = out;                       // [B,K,5]
    float* scores = out + (size_t)B_ * K_ * 5; // [B,K]
    float* validf = out + (size_t)B_ * K_ * 6; // [B,K]

    for (int k = tid; k < K_; k += 1024) {
        int o = b * K_ + k;
        unsigned long long key = cand[k];
        unsigned int bits = (unsigned int)(key >> 32);
        if (bits == 0u) {
            rois[o * 5 + 0] = 0.0f; rois[o * 5 + 1] = 0.0f;
            rois[o * 5 + 2] = 0.0f; rois[o * 5 + 3] = 0.0f;
            rois[o * 5 + 4] = 0.0f;
            scores[o] = 0.0f; validf[o] = 0.0f;
        } else {
            float v = __uint_as_float(bits);
            unsigned int idx = 0xFFFFFFFFu - (unsigned int)(key & 0xFFFFFFFFull);
            int y = (int)(idx >> 9), x = (int)(idx & 511u);
            float cx = ((float)x + 0.5f) * 4.0f;
            float cy = ((float)y + 0.5f) * 4.0f;
            float ss = sigmoid_fast(scale[(size_t)b * HW_ + idx]);
            float su = sigmoid_fast(unc  [(size_t)b * HW_ + idx]);
            float side = (32.0f + ss * 480.0f) * (1.0f + 0.25f * su);
            float half = 0.5f * side;
            float x1 = fminf(fmaxf(cx - half, 0.0f), fiw - 1.0f);
            float y1 = fminf(fmaxf(cy - half, 0.0f), fih - 1.0f);
            float x2 = fminf(fmaxf(cx + half, 1.0f), fiw);
            float y2 = fminf(fmaxf(cy + half, 1.0f), fih);
            rois[o * 5 + 0] = (float)b;
            rois[o * 5 + 1] = x1; rois[o * 5 + 2] = y1;
            rois[o * 5 + 3] = x2; rois[o * 5 + 4] = y2;
            scores[o] = v; validf[o] = 1.0f;
        }
    }
}

extern "C" void kernel_launch(void* const* d_in, const int* in_sizes, int n_in,
                              void* d_out, int out_size, void* d_ws, size_t ws_size,
                              hipStream_t stream) {
    const float* route = (const float*)d_in[0];
    const float* scale = (const float*)d_in[1];
    const float* unc   = (const float*)d_in[2];
    const int*   ih    = (const int*)d_in[3];
    const int*   iw    = (const int*)d_in[4];
    float* out = (float*)d_out;

    // ws layout:
    //   plist  9,830,400 B  (32 x 38400 x u64)  — fully rewritten each launch
    //   ghist    524,288 B  (32 x 4096 x u32)   — memset to 0 each launch
    //   gcnt         128 B  (32 x i32)          — memset to 0 each launch
    //   gcand    524,288 B  (32 x 2048 x u64)   — only [0, gcnt[b]) read
    unsigned char* base = (unsigned char*)d_ws;
    unsigned long long* plist = (unsigned long long*)base;
    unsigned int* ghist = (unsigned int*)(base + PL_BYTES_);
    int* gcnt           = (int*)(base + PL_BYTES_ + GH_BYTES_);
    unsigned long long* gcand =
        (unsigned long long*)(base + PL_BYTES_ + GH_BYTES_ + 128);

    hipMemsetAsync(ghist, 0, GH_BYTES_ + 128, stream);

    dim3 g(NSTRIP_, B_);      // 32 strips x 32 batches
    fused_peak_kernel<<<g, THR_, 0, stream>>>(route, unc, plist, ghist);
    dim3 gg(GSPLIT_, B_);     // 8 splits x 32 batches
    gather_kernel<<<gg, 1024, 0, stream>>>(plist, ghist, gcnt, gcand);
    sort_emit_kernel<<<B_, 1024, 0, stream>>>(scale, unc, gcand, gcnt,
                                              ih, iw, out);
}

// Round 2
// 185.018 us; speedup vs baseline: 1.4657x; 1.4657x over previous
//
#include <hip/hip_runtime.h>
#include <hip/hip_bf16.h>
#include <math.h>

// H2R detector: score map -> 3x3 NMS peaks -> per-batch top-1000 -> ROIs.
// [B=32,1,512,512] fp32 inputs; out = rois[32,1000,5] ++ scores[32,1000]
// ++ valid[32,1000] = 224000 floats.
//
// Scoring replicates numpy's SIMD (Cephes) fp32 expf op-for-op (verified
// bit-exact rounds 5-10: absmax 0.0). DO NOT alter score or emit paths.
//
// Round 13: kill all contended returning atomics (round 12's gather did
// device-scope atomicAdd-with-return on 32 hot words -> 104us serialization,
// VALUBusy 0.7%).
//   - fused_peak: per-WAVE private plist segments (cap 176, mean ~114,
//     ~7 sigma). Append via ballot+popcount running register counter: no
//     atomic, no shfl broadcast, no lcnt. Each wave zero-fills its own tail.
//     Hist stays in the dead-sm[] LDS overlay -> global merge (unchanged).
//   - gather: per-(batch,split) private gcand segment + LDS counter; count
//     stored with a plain store to gcnt8. Zero global atomics.
//   - sort_emit: compacts the 8 split segments via counts, then verified
//     bitonic + emit verbatim (full 64-bit key sort makes order irrelevant).

#define B_   32
#define H_   512
#define W_   512
#define HW_  (H_ * W_)
#define K_   1000
#define ROWS_ 16            // interior rows per strip
#define THR_  512           // threads per fused block (8 waves)
#define NSTRIP_ 32          // H_/ROWS_
#define WSEGCAP_ 176        // per-wave peak capacity (mean ~114; even -> 16B align)
#define STRIPCAP_ (8 * WSEGCAP_)     // 1408 slots per strip
#define NSLOT_ (NSTRIP_ * STRIPCAP_) // 45056 slots per batch
#define NPAIR_ (NSLOT_ / 2)          // 22528 ulonglong2 pairs
#define CAND_ 2048          // candidate sort buffer (power of 2)
#define NBUK_ 4096          // score buckets = bits >> 18 (score < 1.0)
#define GSPLIT_ 8           // gather blocks per batch
#define SPLITCAP_ 512       // per-split candidate capacity (mean ~215)

#define PL_BYTES_ ((size_t)B_ * NSLOT_ * 8)       // 11,534,336
#define GH_BYTES_ ((size_t)B_ * NBUK_ * 4)        // 524,288
#define GC_BYTES_ ((size_t)B_ * GSPLIT_ * 4)      // 1,024
#define CD_BYTES_ ((size_t)B_ * GSPLIT_ * SPLITCAP_ * 8)  // 1,048,576

// ---- numpy SIMD (Cephes) fp32 exp replica — bit-exact, do not touch -------
__device__ __forceinline__ float np_expf(float x) {
#pragma clang fp contract(off)
    const float log2e = 1.44269504088896341f;
    float z = x * log2e;
    float m = rintf(z);
    float r = fmaf(m, -0.693359375f, x);
    r = fmaf(m, 2.12194440e-4f, r);
    float r2 = r * r;
    float p = fmaf(1.9875691500e-4f, r, 1.3981999507e-3f);
    p = fmaf(p, r, 8.3334519073e-3f);
    p = fmaf(p, r, 4.1665795894e-2f);
    p = fmaf(p, r, 1.6666665459e-1f);
    p = fmaf(p, r, 5.0000001201e-1f);
    p = fmaf(p, r2, r);
    p = p + 1.0f;
    int mi = (int)m;
    float sc = __int_as_float((127 + mi) << 23);
    return p * sc;
}

__device__ __forceinline__ float sigmoid_np(float x) {
#pragma clang fp contract(off)
    float e = np_expf(-x);
    float d = 1.0f + e;
    return 1.0f / d;
}

__device__ __forceinline__ float score_ref(float r, float u) {
#pragma clang fp contract(off)
    float s  = sigmoid_np(r);
    float s2 = s * s;
    float su = sigmoid_np(u);
    float t  = 0.35f * su;
    float m  = 1.0f - t;
    return s2 * m;
}

__device__ __forceinline__ float sigmoid_fast(float x) {  // box geometry only
    return 1.0f / (1.0f + __expf(-x));
}

// ---- Fused: score strip + 3x3 peak test -> per-wave segments + hist -------
__global__ __launch_bounds__(THR_, 4) void fused_peak_kernel(
    const float* __restrict__ route, const float* __restrict__ unc,
    unsigned long long* __restrict__ plist,
    unsigned int* __restrict__ ghist)
{
    __shared__ float sm[ROWS_ + 2][W_];          // 18x512 = 36.9 KB

    const int tid   = threadIdx.x;
    const int lane  = tid & 63;
    const int wid   = tid >> 6;                  // 0..7
    const int strip = blockIdx.x;                // 0..31
    const int b     = blockIdx.y;                // 0..31
    const int r0    = strip * ROWS_;

    const float4* rb4 = (const float4*)(route + (size_t)b * HW_);
    const float4* ub4 = (const float4*)(unc   + (size_t)b * HW_);
    unsigned long long* wseg =
        plist + (size_t)(b * NSTRIP_ + strip) * STRIPCAP_ + wid * WSEGCAP_;

    // Stage 18 halo rows: branchless (slot clamp), 10 loads in flight.
    float4 rv[5], uv[5];
    int lrow[5], c4[5]; bool ok[5];
    #pragma unroll
    for (int k = 0; k < 5; ++k) {
        int slot = tid + k * THR_;
        slot = slot < 2303 ? slot : 2303;
        int row = slot >> 7;
        int gy  = r0 - 1 + row;
        lrow[k] = row; c4[k] = slot & 127;
        ok[k]   = (gy >= 0 && gy < H_);
        int cy  = gy < 0 ? 0 : (gy >= H_ ? H_ - 1 : gy);
        rv[k] = rb4[cy * 128 + c4[k]];
        uv[k] = ub4[cy * 128 + c4[k]];
    }
    #pragma unroll
    for (int k = 0; k < 5; ++k) {
        float4 s;
        s.x = score_ref(rv[k].x, uv[k].x);
        s.y = score_ref(rv[k].y, uv[k].y);
        s.z = score_ref(rv[k].z, uv[k].z);
        s.w = score_ref(rv[k].w, uv[k].w);
        if (!ok[k]) { s.x = -INFINITY; s.y = -INFINITY;
                      s.z = -INFINITY; s.w = -INFINITY; }
        *(float4*)&sm[lrow[k]][c4[k] * 4] = s;
    }
    __syncthreads();

    // Peak test: 16x512 interior, 4-px groups, float4 reads + column max.
    // Per-wave append: ballot + popcount running counter (no atomics).
    const unsigned long long lt = (1ull << lane) - 1ull;
    int wn = 0;                                  // wave-uniform running count
    unsigned int hreg[8];
    #pragma unroll
    for (int j = 0; j < 4; ++j) {
        int g  = tid + j * THR_;                 // 0..2047
        int ly = 1 + (g >> 7);                   // 1..16
        int x0 = (g & 127) * 4;
        int gy = r0 + (ly - 1);
        float4 q0 = *(const float4*)&sm[ly - 1][x0];
        float4 q1 = *(const float4*)&sm[ly    ][x0];
        float4 q2 = *(const float4*)&sm[ly + 1][x0];
        bool hasL = (x0 > 0), hasR = (x0 + 4 < W_);
        float l0 = hasL ? sm[ly - 1][x0 - 1] : -INFINITY;
        float l1 = hasL ? sm[ly    ][x0 - 1] : -INFINITY;
        float l2 = hasL ? sm[ly + 1][x0 - 1] : -INFINITY;
        float e0 = hasR ? sm[ly - 1][x0 + 4] : -INFINITY;
        float e1 = hasR ? sm[ly    ][x0 + 4] : -INFINITY;
        float e2 = hasR ? sm[ly + 1][x0 + 4] : -INFINITY;
        float f_m1 = fmaxf(l0, fmaxf(l1, l2));
        float f_0  = fmaxf(q0.x, fmaxf(q1.x, q2.x));
        float f_1  = fmaxf(q0.y, fmaxf(q1.y, q2.y));
        float f_2  = fmaxf(q0.z, fmaxf(q1.z, q2.z));
        float f_3  = fmaxf(q0.w, fmaxf(q1.w, q2.w));
        float f_4  = fmaxf(e0, fmaxf(e1, e2));
        float tb0  = fmaxf(q0.x, q2.x);
        float tb1  = fmaxf(q0.y, q2.y);
        float tb2  = fmaxf(q0.z, q2.z);
        float tb3  = fmaxf(q0.w, q2.w);
        float vv[4] = { q1.x, q1.y, q1.z, q1.w };
        float mm[4];
        mm[0] = fmaxf(fmaxf(f_m1, f_1), tb0);
        mm[1] = fmaxf(fmaxf(f_0,  f_2), tb1);
        mm[2] = fmaxf(fmaxf(f_1,  f_3), tb2);
        mm[3] = fmaxf(fmaxf(f_2,  f_4), tb3);
        unsigned int pk01 = 0u, pk23 = 0u;
        #pragma unroll
        for (int i = 0; i < 4; ++i) {
            bool take = (vv[i] >= mm[i]);
            unsigned long long mk = __ballot(take);
            if (take) {
                int p = wn + __popcll(mk & lt);
                if (p < WSEGCAP_) {
                    unsigned int bits = __float_as_uint(vv[i]);
                    unsigned int idx  = (unsigned int)(gy * W_ + x0 + i);
                    wseg[p] = ((unsigned long long)bits << 32)
                              | (0xFFFFFFFFu - idx);
                    unsigned int bkt = bits >> 18;   // <4096, fits 16b
                    if (i < 2) pk01 |= bkt << (16 * i);
                    else       pk23 |= bkt << (16 * (i - 2));
                }
            }
            wn += __popcll(mk);
        }
        hreg[2 * j]     = pk01;
        hreg[2 * j + 1] = pk23;
    }
    // Zero-fill this wave's tail so gather can stream unconditionally.
    for (int i = (wn < WSEGCAP_ ? wn : WSEGCAP_) + lane; i < WSEGCAP_; i += 64)
        wseg[i] = 0ull;
    __syncthreads();

    // sm[] is dead now: overlay a 4096 x u32 histogram (16 KB of 36.9 KB).
    unsigned int* hist = (unsigned int*)&sm[0][0];
    for (int i = tid; i < NBUK_; i += THR_) hist[i] = 0u;
    __syncthreads();

    #pragma unroll
    for (int j = 0; j < 8; ++j) {
        unsigned int h  = hreg[j];
        unsigned int b0 = h & 0xFFFFu;
        unsigned int b1 = h >> 16;
        if (b0) atomicAdd(&hist[b0], 1u);
        if (b1) atomicAdd(&hist[b1], 1u);
    }
    __syncthreads();

    // Merge nonzero buckets into the global per-batch histogram.
    unsigned int* gh = ghist + (size_t)b * NBUK_;
    for (int i = tid; i < NBUK_; i += THR_) {
        unsigned int c = hist[i];
        if (c) atomicAdd(&gh[i], c);
    }
}

// ---- Gather: per-block T-scan -> private split segment (LDS counter) ------
__global__ __launch_bounds__(1024) void gather_kernel(
    const unsigned long long* __restrict__ plist,
    const unsigned int* __restrict__ ghist,
    int* __restrict__ gcnt8,
    unsigned long long* __restrict__ gcand)
{
    __shared__ int sh_T, sh_n;

    const int sp  = blockIdx.x;                  // 0..GSPLIT_-1
    const int b   = blockIdx.y;                  // 0..31
    const int tid = threadIdx.x;
    const int lane = tid & 63, wid = tid >> 6;

    const ulonglong2* p2 = (const ulonglong2*)(plist + (size_t)b * NSLOT_);
    const int i0 = sp * (NPAIR_ / GSPLIT_);
    const int i1 = i0 + (NPAIR_ / GSPLIT_);

    // Preload this block's slice (<=3 iters) so loads overlap the T-scan.
    ulonglong2 a[3]; int ni = 0;
    {
        int k = 0;
        for (int i = i0 + tid; i < i1; i += 1024, ++k) a[k] = p2[i];
        ni = k;
    }

    // Wave 0: largest bucket T with count(>=T) >= K (early-break from top).
    if (tid == 0) { sh_T = 0; sh_n = 0; }
    if (wid == 0) {
        const unsigned int* gh = ghist + (size_t)b * NBUK_;
        int total = 0;
        for (int c = NBUK_ / 64 - 1; c >= 0; --c) {
            int cnt = (int)gh[c * 64 + lane];
            int sum = cnt;
            #pragma unroll
            for (int off = 32; off > 0; off >>= 1)
                sum += __shfl_down(sum, off, 64);
            sum = __shfl(sum, 0, 64);
            if (total + sum < K_) { total += sum; continue; }
            int suf = cnt;
            #pragma unroll
            for (int off = 1; off < 64; off <<= 1) {
                int o = __shfl_down(suf, off, 64);
                suf += (lane + off < 64) ? o : 0;
            }
            bool cond = (total + suf) >= K_;
            unsigned long long mask = __ballot(cond);
            int ls = 63 - __builtin_clzll(mask);
            if (lane == 0) sh_T = c * 64 + ls;
            break;
        }
    }
    __syncthreads();
    unsigned int T = (unsigned int)sh_T;
    if (T == 0u) T = 1u;   // never gather zero-keys (padding)

    // Append survivors to this block's PRIVATE segment (LDS counter only).
    unsigned long long* cd =
        gcand + ((size_t)b * GSPLIT_ + sp) * SPLITCAP_;
    for (int k = 0; k < ni; ++k) {
        unsigned long long ks[2] = { a[k].x, a[k].y };
        #pragma unroll
        for (int q = 0; q < 2; ++q) {
            bool take = ((((unsigned int)(ks[q] >> 32))) >> 18) >= T;
            unsigned long long mk = __ballot(take);
            if (mk) {
                int ldr = __ffsll((unsigned long long)mk) - 1;
                int base_ = 0;
                if (lane == ldr) base_ = atomicAdd(&sh_n, __popcll(mk));
                base_ = __shfl(base_, ldr, 64);
                if (take) {
                    int p = base_ + __popcll(mk & ((1ull << lane) - 1ull));
                    if (p < SPLITCAP_) cd[p] = ks[q];
                }
            }
        }
    }
    __syncthreads();
    if (tid == 0) {
        int n = sh_n; if (n > SPLITCAP_) n = SPLITCAP_;
        gcnt8[b * GSPLIT_ + sp] = n;
    }
}

// ---- Sort + emit: compact 8 segments, bitonic (desc), verified emit -------
__global__ __launch_bounds__(1024) void sort_emit_kernel(
    const float* __restrict__ scale, const float* __restrict__ unc,
    const unsigned long long* __restrict__ gcand,
    const int* __restrict__ gcnt8,
    const int* __restrict__ ih_p, const int* __restrict__ iw_p,
    float* __restrict__ out)
{
    __shared__ unsigned long long cand[CAND_];   // 16 KB
    __shared__ int offs[GSPLIT_ + 1];

    const int b = blockIdx.x, tid = threadIdx.x;
    if (tid == 0) {
        int r = 0;
        #pragma unroll
        for (int s = 0; s < GSPLIT_; ++s) {
            offs[s] = r;
            r += gcnt8[b * GSPLIT_ + s];
        }
        offs[GSPLIT_] = r;
    }
    __syncthreads();
    int nc = offs[GSPLIT_]; if (nc > CAND_) nc = CAND_;
    int sortN = (nc <= 1024) ? 1024 : CAND_;

    // Compact the 8 split segments into cand[0..nc); zero-fill [nc, sortN).
    const unsigned long long* cd = gcand + (size_t)b * GSPLIT_ * SPLITCAP_;
    for (int i = tid; i < GSPLIT_ * SPLITCAP_; i += 1024) {
        int s = i >> 9;                          // i / SPLITCAP_
        int k = i & (SPLITCAP_ - 1);
        int c0 = offs[s];
        if (k < offs[s + 1] - c0) {
            int d = c0 + k;
            if (d < CAND_) cand[d] = cd[i];
        }
    }
    for (int i = tid; i < sortN; i += 1024)
        if (i >= nc) cand[i] = 0ull;

    // Pair-indexed bitonic sort (desc, exact 64-bit key)
    for (int kk = 2; kk <= sortN; kk <<= 1) {
        for (int jj = kk >> 1; jj > 0; jj >>= 1) {
            __syncthreads();
            for (int p = tid; p < (sortN >> 1); p += 1024) {
                int i   = ((p & ~(jj - 1)) << 1) | (p & (jj - 1));
                int ixj = i | jj;
                bool desc = ((i & kk) == 0);
                unsigned long long a = cand[i], c2 = cand[ixj];
                if (desc ? (a < c2) : (a > c2)) { cand[i] = c2; cand[ixj] = a; }
            }
        }
    }
    __syncthreads();

    // Emit top-K (verified path — do not touch)
    const float fih = (float)(*ih_p);
    const float fiw = (float)(*iw_p);
    float* rois   = out;                       // [B,K,5]
    float* scores = out + (size_t)B_ * K_ * 5; // [B,K]
    float* validf = out + (size_t)B_ * K_ * 6; // [B,K]

    for (int k = tid; k < K_; k += 1024) {
        int o = b * K_ + k;
        unsigned long long key = cand[k];
        unsigned int bits = (unsigned int)(key >> 32);
        if (bits == 0u) {
            rois[o * 5 + 0] = 0.0f; rois[o * 5 + 1] = 0.0f;
            rois[o * 5 + 2] = 0.0f; rois[o * 5 + 3] = 0.0f;
            rois[o * 5 + 4] = 0.0f;
            scores[o] = 0.0f; validf[o] = 0.0f;
        } else {
            float v = __uint_as_float(bits);
            unsigned int idx = 0xFFFFFFFFu - (unsigned int)(key & 0xFFFFFFFFull);
            int y = (int)(idx >> 9), x = (int)(idx & 511u);
            float cx = ((float)x + 0.5f) * 4.0f;
            float cy = ((float)y + 0.5f) * 4.0f;
            float ss = sigmoid_fast(scale[(size_t)b * HW_ + idx]);
            float su = sigmoid_fast(unc  [(size_t)b * HW_ + idx]);
            float side = (32.0f + ss * 480.0f) * (1.0f + 0.25f * su);
            float half = 0.5f * side;
            float x1 = fminf(fmaxf(cx - half, 0.0f), fiw - 1.0f);
            float y1 = fminf(fmaxf(cy - half, 0.0f), fih - 1.0f);
            float x2 = fminf(fmaxf(cx + half, 1.0f), fiw);
            float y2 = fminf(fmaxf(cy + half, 1.0f), fih);
            rois[o * 5 + 0] = (float)b;
            rois[o * 5 + 1] = x1; rois[o * 5 + 2] = y1;
            rois[o * 5 + 3] = x2; rois[o * 5 + 4] = y2;
            scores[o] = v; validf[o] = 1.0f;
        }
    }
}

extern "C" void kernel_launch(void* const* d_in, const int* in_sizes, int n_in,
                              void* d_out, int out_size, void* d_ws, size_t ws_size,
                              hipStream_t stream) {
    const float* route = (const float*)d_in[0];
    const float* scale = (const float*)d_in[1];
    const float* unc   = (const float*)d_in[2];
    const int*   ih    = (const int*)d_in[3];
    const int*   iw    = (const int*)d_in[4];
    float* out = (float*)d_out;

    // ws layout:
    //   plist  11,534,336 B (32 x 45056 x u64)  — fully rewritten each launch
    //   ghist     524,288 B (32 x 4096 x u32)   — memset to 0 each launch
    //   gcnt8       1,024 B (32 x 8 x i32)      — plain-stored each launch
    //   gcand   1,048,576 B (32 x 8 x 512 x u64)— only counted prefixes read
    unsigned char* base = (unsigned char*)d_ws;
    unsigned long long* plist = (unsigned long long*)base;
    unsigned int* ghist = (unsigned int*)(base + PL_BYTES_);
    int* gcnt8          = (int*)(base + PL_BYTES_ + GH_BYTES_);
    unsigned long long* gcand =
        (unsigned long long*)(base + PL_BYTES_ + GH_BYTES_ + GC_BYTES_);

    hipMemsetAsync(ghist, 0, GH_BYTES_, stream);

    dim3 g(NSTRIP_, B_);      // 32 strips x 32 batches
    fused_peak_kernel<<<g, THR_, 0, stream>>>(route, unc, plist, ghist);
    dim3 gg(GSPLIT_, B_);     // 8 splits x 32 batches
    gather_kernel<<<gg, 1024, 0, stream>>>(plist, ghist, gcnt8, gcand);
    sort_emit_kernel<<<B_, 1024, 0, stream>>>(scale, unc, gcand, gcnt8,
                                              ih, iw, out);
}

// Round 3
// 164.470 us; speedup vs baseline: 1.6488x; 1.1249x over previous
//
#include <hip/hip_runtime.h>
#include <hip/hip_bf16.h>
#include <math.h>

// H2R detector: score map -> 3x3 NMS peaks -> per-batch top-1000 -> ROIs.
// [B=32,1,512,512] fp32 inputs; out = rois[32,1000,5] ++ scores[32,1000]
// ++ valid[32,1000] = 224000 floats.
//
// Scoring replicates numpy's SIMD (Cephes) fp32 expf op-for-op (verified
// bit-exact rounds 5-10: absmax 0.0). DO NOT alter score or emit paths.
//
// Round 14: histogram-rank backend replaces sort entirely; 2 dispatches.
//   - fused_peak: per-wave atomic-free appends (R13, kept); per-strip packed
//     u16x2 hist written with PLAIN stores (no global atomics, no memset
//     dispatch needed).
//   - select2 (32 blocks): sum 32 strip-hists -> LDS hist -> T-scan ->
//     suffix-sum bucket cursors -> single plist stream scatters survivors
//     bucket-grouped into LDS -> exact descending rank = suffix_start +
//     |{same-bucket keys > mine}| (keys unique -> identical order to the
//     old bitonic, ties included) -> emit directly at slot=rank.
//     Kills: bitonic (66 LDS passes), gcand global round-trip, memset,
//     2 of 4 launch gaps.

#define B_   32
#define H_   512
#define W_   512
#define HW_  (H_ * W_)
#define K_   1000
#define ROWS_ 16            // interior rows per strip
#define THR_  512           // threads per fused block (8 waves)
#define NSTRIP_ 32          // H_/ROWS_
#define WSEGCAP_ 176        // per-wave peak capacity (mean ~114; even -> 16B align)
#define STRIPCAP_ (8 * WSEGCAP_)     // 1408 slots per strip
#define NSLOT_ (NSTRIP_ * STRIPCAP_) // 45056 slots per batch
#define NPAIR_ (NSLOT_ / 2)          // 22528 ulonglong2 pairs
#define NBUK_ 4096          // score buckets = bits >> 18 (score < 1.0)
#define NW2_  (NBUK_ / 2)   // packed u16x2 words per strip hist
#define GCAP_ 2048          // grouped-candidate LDS capacity (nc ~ 1000-1150)

#define PL_BYTES_  ((size_t)B_ * NSLOT_ * 8)              // 11,534,336
#define GH2_BYTES_ ((size_t)B_ * NSTRIP_ * NW2_ * 4)      // 8,388,608

// ---- numpy SIMD (Cephes) fp32 exp replica — bit-exact, do not touch -------
__device__ __forceinline__ float np_expf(float x) {
#pragma clang fp contract(off)
    const float log2e = 1.44269504088896341f;
    float z = x * log2e;
    float m = rintf(z);
    float r = fmaf(m, -0.693359375f, x);
    r = fmaf(m, 2.12194440e-4f, r);
    float r2 = r * r;
    float p = fmaf(1.9875691500e-4f, r, 1.3981999507e-3f);
    p = fmaf(p, r, 8.3334519073e-3f);
    p = fmaf(p, r, 4.1665795894e-2f);
    p = fmaf(p, r, 1.6666665459e-1f);
    p = fmaf(p, r, 5.0000001201e-1f);
    p = fmaf(p, r2, r);
    p = p + 1.0f;
    int mi = (int)m;
    float sc = __int_as_float((127 + mi) << 23);
    return p * sc;
}

__device__ __forceinline__ float sigmoid_np(float x) {
#pragma clang fp contract(off)
    float e = np_expf(-x);
    float d = 1.0f + e;
    return 1.0f / d;
}

__device__ __forceinline__ float score_ref(float r, float u) {
#pragma clang fp contract(off)
    float s  = sigmoid_np(r);
    float s2 = s * s;
    float su = sigmoid_np(u);
    float t  = 0.35f * su;
    float m  = 1.0f - t;
    return s2 * m;
}

__device__ __forceinline__ float sigmoid_fast(float x) {  // box geometry only
    return 1.0f / (1.0f + __expf(-x));
}

// ---- Fused: score strip + 3x3 peak test -> per-wave segments + strip hist -
__global__ __launch_bounds__(THR_, 4) void fused_peak_kernel(
    const float* __restrict__ route, const float* __restrict__ unc,
    unsigned long long* __restrict__ plist,
    unsigned int* __restrict__ ghist2)
{
    __shared__ float sm[ROWS_ + 2][W_];          // 18x512 = 36.9 KB

    const int tid   = threadIdx.x;
    const int lane  = tid & 63;
    const int wid   = tid >> 6;                  // 0..7
    const int strip = blockIdx.x;                // 0..31
    const int b     = blockIdx.y;                // 0..31
    const int r0    = strip * ROWS_;

    const float4* rb4 = (const float4*)(route + (size_t)b * HW_);
    const float4* ub4 = (const float4*)(unc   + (size_t)b * HW_);
    unsigned long long* wseg =
        plist + (size_t)(b * NSTRIP_ + strip) * STRIPCAP_ + wid * WSEGCAP_;

    // Stage 18 halo rows: branchless (slot clamp), 10 loads in flight.
    float4 rv[5], uv[5];
    int lrow[5], c4[5]; bool ok[5];
    #pragma unroll
    for (int k = 0; k < 5; ++k) {
        int slot = tid + k * THR_;
        slot = slot < 2303 ? slot : 2303;
        int row = slot >> 7;
        int gy  = r0 - 1 + row;
        lrow[k] = row; c4[k] = slot & 127;
        ok[k]   = (gy >= 0 && gy < H_);
        int cy  = gy < 0 ? 0 : (gy >= H_ ? H_ - 1 : gy);
        rv[k] = rb4[cy * 128 + c4[k]];
        uv[k] = ub4[cy * 128 + c4[k]];
    }
    #pragma unroll
    for (int k = 0; k < 5; ++k) {
        float4 s;
        s.x = score_ref(rv[k].x, uv[k].x);
        s.y = score_ref(rv[k].y, uv[k].y);
        s.z = score_ref(rv[k].z, uv[k].z);
        s.w = score_ref(rv[k].w, uv[k].w);
        if (!ok[k]) { s.x = -INFINITY; s.y = -INFINITY;
                      s.z = -INFINITY; s.w = -INFINITY; }
        *(float4*)&sm[lrow[k]][c4[k] * 4] = s;
    }
    __syncthreads();

    // Peak test: 16x512 interior, 4-px groups, float4 reads + column max.
    // Per-wave append: ballot + popcount running counter (no atomics).
    const unsigned long long lt = (1ull << lane) - 1ull;
    int wn = 0;                                  // wave-uniform running count
    unsigned int hreg[8];
    #pragma unroll
    for (int j = 0; j < 4; ++j) {
        int g  = tid + j * THR_;                 // 0..2047
        int ly = 1 + (g >> 7);                   // 1..16
        int x0 = (g & 127) * 4;
        int gy = r0 + (ly - 1);
        float4 q0 = *(const float4*)&sm[ly - 1][x0];
        float4 q1 = *(const float4*)&sm[ly    ][x0];
        float4 q2 = *(const float4*)&sm[ly + 1][x0];
        bool hasL = (x0 > 0), hasR = (x0 + 4 < W_);
        float l0 = hasL ? sm[ly - 1][x0 - 1] : -INFINITY;
        float l1 = hasL ? sm[ly    ][x0 - 1] : -INFINITY;
        float l2 = hasL ? sm[ly + 1][x0 - 1] : -INFINITY;
        float e0 = hasR ? sm[ly - 1][x0 + 4] : -INFINITY;
        float e1 = hasR ? sm[ly    ][x0 + 4] : -INFINITY;
        float e2 = hasR ? sm[ly + 1][x0 + 4] : -INFINITY;
        float f_m1 = fmaxf(l0, fmaxf(l1, l2));
        float f_0  = fmaxf(q0.x, fmaxf(q1.x, q2.x));
        float f_1  = fmaxf(q0.y, fmaxf(q1.y, q2.y));
        float f_2  = fmaxf(q0.z, fmaxf(q1.z, q2.z));
        float f_3  = fmaxf(q0.w, fmaxf(q1.w, q2.w));
        float f_4  = fmaxf(e0, fmaxf(e1, e2));
        float tb0  = fmaxf(q0.x, q2.x);
        float tb1  = fmaxf(q0.y, q2.y);
        float tb2  = fmaxf(q0.z, q2.z);
        float tb3  = fmaxf(q0.w, q2.w);
        float vv[4] = { q1.x, q1.y, q1.z, q1.w };
        float mm[4];
        mm[0] = fmaxf(fmaxf(f_m1, f_1), tb0);
        mm[1] = fmaxf(fmaxf(f_0,  f_2), tb1);
        mm[2] = fmaxf(fmaxf(f_1,  f_3), tb2);
        mm[3] = fmaxf(fmaxf(f_2,  f_4), tb3);
        unsigned int pk01 = 0u, pk23 = 0u;
        #pragma unroll
        for (int i = 0; i < 4; ++i) {
            bool take = (vv[i] >= mm[i]);
            unsigned long long mk = __ballot(take);
            if (take) {
                int p = wn + __popcll(mk & lt);
                if (p < WSEGCAP_) {
                    unsigned int bits = __float_as_uint(vv[i]);
                    unsigned int idx  = (unsigned int)(gy * W_ + x0 + i);
                    wseg[p] = ((unsigned long long)bits << 32)
                              | (0xFFFFFFFFu - idx);
                    unsigned int bkt = bits >> 18;   // <4096, fits 16b
                    if (i < 2) pk01 |= bkt << (16 * i);
                    else       pk23 |= bkt << (16 * (i - 2));
                }
            }
            wn += __popcll(mk);
        }
        hreg[2 * j]     = pk01;
        hreg[2 * j + 1] = pk23;
    }
    // Zero-fill this wave's tail so select2 can stream unconditionally.
    for (int i = (wn < WSEGCAP_ ? wn : WSEGCAP_) + lane; i < WSEGCAP_; i += 64)
        wseg[i] = 0ull;
    __syncthreads();

    // sm[] is dead now: overlay a packed u16x2 hist (2048 words, 8 KB).
    unsigned int* hist = (unsigned int*)&sm[0][0];
    for (int i = tid; i < NW2_; i += THR_) hist[i] = 0u;
    __syncthreads();

    #pragma unroll
    for (int j = 0; j < 8; ++j) {
        unsigned int h  = hreg[j];
        unsigned int b0 = h & 0xFFFFu;
        unsigned int b1 = h >> 16;
        if (b0) atomicAdd(&hist[b0 >> 1], 1u << ((b0 & 1) * 16));
        if (b1) atomicAdd(&hist[b1 >> 1], 1u << ((b1 & 1) * 16));
    }
    __syncthreads();

    // PLAIN coalesced stores of this strip's hist (no zeroed global needed).
    unsigned int* gh2 = ghist2 + (size_t)(b * NSTRIP_ + strip) * NW2_;
    for (int i = tid; i < NW2_; i += THR_) gh2[i] = hist[i];
}

// ---- select2: hist-sum -> T -> cursors -> scatter -> rank -> emit ---------
__global__ __launch_bounds__(1024) void select2_kernel(
    const float* __restrict__ scale, const float* __restrict__ unc,
    const unsigned long long* __restrict__ plist,
    const unsigned int* __restrict__ ghist2,
    const int* __restrict__ ih_p, const int* __restrict__ iw_p,
    float* __restrict__ out)
{
    __shared__ unsigned int hist[NBUK_];          // 16 KB: per-batch counts
    __shared__ unsigned int cursor[NBUK_];        // 16 KB: scatter cursors
    __shared__ unsigned long long grp[GCAP_];     // 16 KB: bucket-grouped keys
    __shared__ int sh_T, sh_nc;

    const int b = blockIdx.x, tid = threadIdx.x;
    const int lane = tid & 63, wid = tid >> 6;

    // Phase A: sum the 32 per-strip packed hists -> u32 hist[4096].
    const unsigned int* gbase = ghist2 + (size_t)b * NSTRIP_ * NW2_;
    for (int w = tid; w < NW2_; w += 1024) {      // 2 iters, coalesced
        unsigned int s0 = 0u, s1 = 0u;
        #pragma unroll
        for (int s = 0; s < NSTRIP_; ++s) {
            unsigned int v = gbase[s * NW2_ + w];
            s0 += v & 0xFFFFu;
            s1 += v >> 16;
        }
        hist[2 * w]     = s0;
        hist[2 * w + 1] = s1;
    }
    __syncthreads();

    // Phase B (wave0): T = largest bucket with count(>=T) >= K, then
    // suffix-sum cursor init for all buckets >= T, and nc = count(>=T).
    if (wid == 0) {
        int Tv = 0;
        int total = 0;
        for (int c = NBUK_ / 64 - 1; c >= 0; --c) {
            int cnt = (int)hist[c * 64 + lane];
            int sum = cnt;
            #pragma unroll
            for (int off = 32; off > 0; off >>= 1)
                sum += __shfl_down(sum, off, 64);
            sum = __shfl(sum, 0, 64);
            if (total + sum < K_) { total += sum; continue; }
            int suf = cnt;
            #pragma unroll
            for (int off = 1; off < 64; off <<= 1) {
                int o = __shfl_down(suf, off, 64);
                suf += (lane + off < 64) ? o : 0;
            }
            bool cond = (total + suf) >= K_;
            unsigned long long mask = __ballot(cond);
            int ls = 63 - __builtin_clzll(mask);
            Tv = c * 64 + ls;                     // wave-uniform
            break;
        }
        if (Tv < 1) Tv = 1;                       // never select zero-pad keys

        // cursor[beta] = #elements in buckets > beta, for beta >= Tv.
        int run = 0;
        for (int cb = NBUK_ - 64; cb >= (Tv & ~63); cb -= 64) {
            int beta = cb + lane;
            int cnt = (beta >= Tv) ? (int)hist[beta] : 0;
            int suf = cnt;                        // suffix-inclusive over lanes
            #pragma unroll
            for (int off = 1; off < 64; off <<= 1) {
                int o = __shfl_down(suf, off, 64);
                suf += (lane + off < 64) ? o : 0;
            }
            int chunk_total = __shfl(suf, 0, 64);
            if (beta >= Tv) cursor[beta] = (unsigned int)(run + (suf - cnt));
            run += chunk_total;
        }
        if (lane == 0) { sh_T = Tv; sh_nc = run; }
    }
    __syncthreads();
    const unsigned int T = (unsigned int)sh_T;

    // Phase C: single plist stream; scatter survivors bucket-grouped.
    {
        const ulonglong2* p2 = (const ulonglong2*)(plist + (size_t)b * NSLOT_);
        for (int i = tid; i < NPAIR_; i += 1024) {  // 22 iters
            ulonglong2 a = p2[i];
            unsigned int b0 = (unsigned int)(a.x >> 50);
            unsigned int b1 = (unsigned int)(a.y >> 50);
            if (b0 >= T) {
                unsigned int pos = atomicAdd(&cursor[b0], 1u);
                if (pos < GCAP_) grp[pos] = a.x;
            }
            if (b1 >= T) {
                unsigned int pos = atomicAdd(&cursor[b1], 1u);
                if (pos < GCAP_) grp[pos] = a.y;
            }
        }
    }
    __syncthreads();

    // Phase D: exact descending rank per candidate + direct emit.
    // rank = (#elements in higher buckets) + (#same-bucket keys > mine).
    // Keys unique (idx in low bits) -> identical order to a full desc sort.
    const float fih = (float)(*ih_p);
    const float fiw = (float)(*iw_p);
    float* rois   = out;                       // [B,K,5]
    float* scores = out + (size_t)B_ * K_ * 5; // [B,K]
    float* validf = out + (size_t)B_ * K_ * 6; // [B,K]

    int nc = sh_nc;
    int ncEff = nc < GCAP_ ? nc : GCAP_;
    for (int p = tid; p < ncEff; p += 1024) {
        unsigned long long key = grp[p];
        unsigned int beta = (unsigned int)(key >> 50);
        int segEnd   = (int)cursor[beta];         // start + cnt
        int segStart = segEnd - (int)hist[beta];
        int qEnd = segEnd < GCAP_ ? segEnd : GCAP_;
        int r = 0;
        for (int q = segStart; q < qEnd; ++q)
            r += (grp[q] > key) ? 1 : 0;
        int rank = segStart + r;
        if (rank < K_) {
            int o = b * K_ + rank;
            unsigned int bits = (unsigned int)(key >> 32);
            float v = __uint_as_float(bits);
            unsigned int idx = 0xFFFFFFFFu - (unsigned int)(key & 0xFFFFFFFFull);
            int y = (int)(idx >> 9), x = (int)(idx & 511u);
            float cx = ((float)x + 0.5f) * 4.0f;
            float cy = ((float)y + 0.5f) * 4.0f;
            float ss = sigmoid_fast(scale[(size_t)b * HW_ + idx]);
            float su = sigmoid_fast(unc  [(size_t)b * HW_ + idx]);
            float side = (32.0f + ss * 480.0f) * (1.0f + 0.25f * su);
            float half = 0.5f * side;
            float x1 = fminf(fmaxf(cx - half, 0.0f), fiw - 1.0f);
            float y1 = fminf(fmaxf(cy - half, 0.0f), fih - 1.0f);
            float x2 = fminf(fmaxf(cx + half, 1.0f), fiw);
            float y2 = fminf(fmaxf(cy + half, 1.0f), fih);
            rois[o * 5 + 0] = (float)b;
            rois[o * 5 + 1] = x1; rois[o * 5 + 2] = y1;
            rois[o * 5 + 3] = x2; rois[o * 5 + 4] = y2;
            scores[o] = v; validf[o] = 1.0f;
        }
    }
    // Tail fill (only if fewer than K candidates exist — normally empty).
    for (int k = nc + tid; k < K_; k += 1024) {
        int o = b * K_ + k;
        rois[o * 5 + 0] = 0.0f; rois[o * 5 + 1] = 0.0f;
        rois[o * 5 + 2] = 0.0f; rois[o * 5 + 3] = 0.0f;
        rois[o * 5 + 4] = 0.0f;
        scores[o] = 0.0f; validf[o] = 0.0f;
    }
}

extern "C" void kernel_launch(void* const* d_in, const int* in_sizes, int n_in,
                              void* d_out, int out_size, void* d_ws, size_t ws_size,
                              hipStream_t stream) {
    const float* route = (const float*)d_in[0];
    const float* scale = (const float*)d_in[1];
    const float* unc   = (const float*)d_in[2];
    const int*   ih    = (const int*)d_in[3];
    const int*   iw    = (const int*)d_in[4];
    float* out = (float*)d_out;

    // ws layout:
    //   plist  11,534,336 B (32 x 45056 x u64)        — fully rewritten
    //   ghist2  8,388,608 B (32 x 32 x 2048 x u32)    — fully rewritten
    // Every word read downstream is freshly written each launch -> no memset.
    unsigned char* base = (unsigned char*)d_ws;
    unsigned long long* plist = (unsigned long long*)base;
    unsigned int* ghist2 = (unsigned int*)(base + PL_BYTES_);

    dim3 g(NSTRIP_, B_);      // 32 strips x 32 batches
    fused_peak_kernel<<<g, THR_, 0, stream>>>(route, unc, plist, ghist2);
    select2_kernel<<<B_, 1024, 0, stream>>>(scale, unc, plist, ghist2,
                                            ih, iw, out);
}